// Round 2
// baseline (256.046 us; speedup 1.0000x reference)
//
#include <hip/hip_runtime.h>
#include <hip/hip_bf16.h>
#include <math.h>

#define CC 1024
#define BB 16
#define DD 128
#define NEGV -1e30f
#define MP 392  // m' LDS row stride: 3*128 + 8 pad (16B-aligned rows)

typedef __attribute__((ext_vector_type(4))) float floatx4;
typedef __attribute__((ext_vector_type(8))) __bf16 bf16x8;
typedef __attribute__((ext_vector_type(8))) int intx8;

__device__ __forceinline__ unsigned short f2bf(float x) {
    unsigned int u = __float_as_uint(x);
    u = (u + 0x7FFFu + ((u >> 16) & 1u)) >> 16;
    return (unsigned short)u;
}
__device__ __forceinline__ float bf2f(unsigned short v) {
    return __uint_as_float((unsigned int)v << 16);
}

// ---------------- merged prep: h transpose/cast + weight cast/combine + stats zero
__global__ __launch_bounds__(256) void prep_all(const float* __restrict__ h,
                                                unsigned short* __restrict__ h_bc,
                                                unsigned short* __restrict__ h_bT,
                                                const float* __restrict__ w1, const float* __restrict__ w2,
                                                const float* __restrict__ wr, const float* __restrict__ wg,
                                                unsigned short* __restrict__ o1, unsigned short* __restrict__ o2,
                                                unsigned short* __restrict__ wc, float* __restrict__ stats) {
    __shared__ float tile[64][65];
    const int bid = blockIdx.x;
    if (bid < 512) {  // prep_h: (c0:16, d0:2, b:16)
        const int c0 = (bid & 15) * 64, d0 = ((bid >> 4) & 1) * 64, b = bid >> 5;
        const int tx = threadIdx.x & 63, ty = threadIdx.x >> 6;
#pragma unroll
        for (int i = 0; i < 16; i++) {
            int cl = ty + i * 4;
            float v = h[((size_t)(c0 + cl) * BB + b) * DD + d0 + tx];
            tile[cl][tx] = v;
            h_bc[((size_t)b * CC + c0 + cl) * DD + d0 + tx] = f2bf(v);
        }
        __syncthreads();
#pragma unroll
        for (int i = 0; i < 16; i++) {
            int dl = ty + i * 4;
            h_bT[((size_t)b * DD + d0 + dl) * CC + c0 + tx] = f2bf(tile[tx][dl]);
        }
    } else if (bid < 576) {  // prep_w
        int i = (bid - 512) * 256 + threadIdx.x;  // 0..16383
        int d = i >> 7, k = i & 127;
        o1[i] = f2bf(w1[i]);
        o2[i] = f2bf(w2[i]);
        const float* pr = wr + (size_t)d * 512;
        const float* pg = wg + (size_t)d * 512;
        wc[(size_t)(0 * 128 + d) * 128 + k] = f2bf(pr[128 + k] - pr[384 + k]);
        wc[(size_t)(1 * 128 + d) * 128 + k] = f2bf(pr[256 + k]);
        wc[(size_t)(2 * 128 + d) * 128 + k] = f2bf(pr[k] + pr[384 + k]);
        wc[(size_t)(3 * 128 + d) * 128 + k] = f2bf(pg[128 + k] - pg[384 + k]);
        wc[(size_t)(4 * 128 + d) * 128 + k] = f2bf(pg[256 + k]);
        wc[(size_t)(5 * 128 + d) * 128 + k] = f2bf(pg[k] + pg[384 + k]);
    } else {  // zero softmax-denominator accumulators (ws is poisoned)
        int i = ((bid - 576) * 256 + threadIdx.x) * 4;
        *(float4*)(stats + i) = float4{0.f, 0.f, 0.f, 0.f};
    }
}

// ---------------- fused exp+mask dual-layout emit (replaces both input softmaxes)
__global__ __launch_bounds__(256) void expmask_dual(const float* __restrict__ B_t,
                                                    const int* __restrict__ mask,
                                                    unsigned char* __restrict__ Em,
                                                    unsigned char* __restrict__ EmT,
                                                    float* __restrict__ rowsum,
                                                    float* __restrict__ colsum) {
    __shared__ float tile[64][65];
    __shared__ float cpart[16][65];
    const int b = blockIdx.z, i0 = blockIdx.x * 64, j0 = blockIdx.y * 64;
    const int tid = threadIdx.x;
    const int rr = tid >> 4, cc = tid & 15;
    const int4 mj4 = *(const int4*)(mask + b * CC + j0 + cc * 4);
    const int4 mi4 = *(const int4*)(mask + b * CC + i0 + cc * 4);
    const float fj[4] = {mj4.x ? 1.f : 0.f, mj4.y ? 1.f : 0.f, mj4.z ? 1.f : 0.f, mj4.w ? 1.f : 0.f};
    const float fi[4] = {mi4.x ? 1.f : 0.f, mi4.y ? 1.f : 0.f, mi4.z ? 1.f : 0.f, mi4.w ? 1.f : 0.f};
    float cp[4] = {0.f, 0.f, 0.f, 0.f};
#pragma unroll
    for (int p = 0; p < 4; p++) {
        const int r = p * 16 + rr;
        float4 v = *(const float4*)(B_t + ((size_t)b * CC + i0 + r) * CC + j0 + cc * 4);
        float e[4] = {__expf(fminf(v.x, 80.f)), __expf(fminf(v.y, 80.f)),
                      __expf(fminf(v.z, 80.f)), __expf(fminf(v.w, 80.f))};
        const float mi_r = mask[b * CC + i0 + r] ? 1.f : 0.f;
        float dsum = 0.f;
#pragma unroll
        for (int u = 0; u < 4; u++) {
            tile[r][cc * 4 + u] = e[u];
            cp[u] += e[u] * mi_r;
            dsum += e[u] * fj[u];
        }
        int pk = __builtin_amdgcn_cvt_pk_fp8_f32(e[0] * fj[0], e[1] * fj[1], 0, false);
        pk = __builtin_amdgcn_cvt_pk_fp8_f32(e[2] * fj[2], e[3] * fj[3], pk, true);
        *(int*)(Em + ((size_t)b * CC + i0 + r) * CC + j0 + cc * 4) = pk;
#pragma unroll
        for (int off = 1; off < 16; off <<= 1) dsum += __shfl_xor(dsum, off, 64);
        if (cc == 0) atomicAdd(&rowsum[b * CC + i0 + r], dsum);
    }
#pragma unroll
    for (int u = 0; u < 4; u++) cpart[rr][cc * 4 + u] = cp[u];
    __syncthreads();
    if (tid < 64) {
        float s = 0.f;
#pragma unroll
        for (int q = 0; q < 16; q++) s += cpart[q][tid];
        atomicAdd(&colsum[b * CC + j0 + tid], s);
    }
#pragma unroll
    for (int p = 0; p < 4; p++) {
        const int r2 = p * 16 + rr;
        float t0 = tile[cc * 4 + 0][r2] * fi[0];
        float t1 = tile[cc * 4 + 1][r2] * fi[1];
        float t2 = tile[cc * 4 + 2][r2] * fi[2];
        float t3 = tile[cc * 4 + 3][r2] * fi[3];
        int pk = __builtin_amdgcn_cvt_pk_fp8_f32(t0, t1, 0, false);
        pk = __builtin_amdgcn_cvt_pk_fp8_f32(t2, t3, pk, true);
        *(int*)(EmT + ((size_t)b * CC + j0 + r2) * CC + i0 + cc * 4) = pk;
    }
}

// ---------------- async staging: rows of 128 BYTES (8x16B chunks), XOR-swizzled
template <int NCH>
__device__ __forceinline__ void stage_async_b(void* dst, const void* src, int ld_bytes) {
    const int w = threadIdx.x >> 6, lane = threadIdx.x & 63;
#pragma unroll
    for (int base = w * 64; base < NCH; base += 256) {
        int ch = base + lane;
        int r = ch >> 3, c = ch & 7;
        int cg = c ^ (r & 7);
        __builtin_amdgcn_global_load_lds(
            (const __attribute__((address_space(1))) void*)((const unsigned char*)src + (size_t)r * ld_bytes + cg * 16),
            (__attribute__((address_space(3))) void*)((unsigned char*)dst + (size_t)base * 16),
            16, 0, 0);
    }
}

template <int TM, int TN>
__device__ __forceinline__ void mfma_tile(const unsigned short (*As)[64], const unsigned short (*Bs)[64],
                                          int arow0, int bcol0, floatx4 (&acc)[TM][TN]) {
    const int lane = threadIdx.x & 63;
    const int l16 = lane & 15, quad = lane >> 4;
    const int sw = l16 & 7;
#pragma unroll
    for (int kk = 0; kk < 2; ++kk) {
        bf16x8 a[TM], b[TN];
#pragma unroll
        for (int tm = 0; tm < TM; tm++)
            a[tm] = *(const bf16x8*)(&As[arow0 + tm * 16 + l16][((kk * 4 + quad) ^ sw) * 8]);
#pragma unroll
        for (int tn = 0; tn < TN; tn++)
            b[tn] = *(const bf16x8*)(&Bs[bcol0 + tn * 16 + l16][((kk * 4 + quad) ^ sw) * 8]);
#pragma unroll
        for (int tm = 0; tm < TM; tm++)
#pragma unroll
            for (int tn = 0; tn < TN; tn++)
                acc[tm][tn] = __builtin_amdgcn_mfma_f32_16x16x32_bf16(a[tm], b[tn], acc[tm][tn], 0, 0, 0);
    }
}

__device__ __forceinline__ void mfma_mixed(const unsigned short* mBase, const unsigned short (*Bs)[64],
                                           int arow0, int bcol0, floatx4 (&acc)[2][4]) {
    const int lane = threadIdx.x & 63;
    const int l16 = lane & 15, quad = lane >> 4;
    const int sw = l16 & 7;
#pragma unroll
    for (int kk = 0; kk < 2; ++kk) {
        bf16x8 a[2], bfr[4];
#pragma unroll
        for (int tm = 0; tm < 2; tm++)
            a[tm] = *(const bf16x8*)(mBase + (size_t)(arow0 + tm * 16 + l16) * MP + kk * 32 + quad * 8);
#pragma unroll
        for (int tn = 0; tn < 4; tn++)
            bfr[tn] = *(const bf16x8*)(&Bs[bcol0 + tn * 16 + l16][((kk * 4 + quad) ^ sw) * 8]);
#pragma unroll
        for (int tm = 0; tm < 2; tm++)
#pragma unroll
            for (int tn = 0; tn < 4; tn++)
                acc[tm][tn] = __builtin_amdgcn_mfma_f32_16x16x32_bf16(a[tm], bfr[tn], acc[tm][tn], 0, 0, 0);
    }
}

// ---------------- h1/h2: relu(h_bc @ W^T + bias), M=16384 N=128 K=128 (dbuf pipeline)
__global__ __launch_bounds__(256) void gemm_h12(const unsigned short* __restrict__ h_bc,
                                                const unsigned short* __restrict__ w1t,
                                                const unsigned short* __restrict__ w2t,
                                                const float* __restrict__ b1, const float* __restrict__ b2,
                                                unsigned short* __restrict__ h1, unsigned short* __restrict__ h2) {
    __shared__ unsigned short As[2][128][64];
    __shared__ unsigned short Bs[2][128][64];
    const unsigned short* W = blockIdx.z ? w2t : w1t;
    const float* bias = blockIdx.z ? b2 : b1;
    unsigned short* out = blockIdx.z ? h2 : h1;
    const int r0 = blockIdx.x * 128;
    const int w = threadIdx.x >> 6, lane = threadIdx.x & 63;
    const int wm = (w >> 1) * 64, wn = (w & 1) * 64;
    floatx4 acc[4][4] = {};
    stage_async_b<1024>(As[0], h_bc + (size_t)r0 * DD, DD * 2);
    stage_async_b<1024>(Bs[0], W, DD * 2);
    for (int kt = 0; kt < 2; kt++) {
        __syncthreads();
        if (kt == 0) {
            stage_async_b<1024>(As[1], h_bc + (size_t)r0 * DD + 64, DD * 2);
            stage_async_b<1024>(Bs[1], W + 64, DD * 2);
        }
        mfma_tile<4, 4>(As[kt], Bs[kt], wm, wn, acc);
    }
    const int quad = lane >> 4, l16 = lane & 15;
#pragma unroll
    for (int tm = 0; tm < 4; tm++)
#pragma unroll
        for (int tn = 0; tn < 4; tn++)
#pragma unroll
            for (int i = 0; i < 4; i++) {
                int row = r0 + wm + tm * 16 + quad * 4 + i;
                int col = wn + tn * 16 + l16;
                float v = acc[tm][tn][i] + bias[col];
                out[(size_t)row * DD + col] = f2bf(fmaxf(v, 0.f));
            }
}

// ---------------- B_new = h1@h2^T + gamma * rinv.cinv.(Em@EmT^T); also emits
//                  per-(row, 64-col-half) softmax stats (max, sum-of-exp) for gemm_fuse
//                  K-loop: double-buffered LDS, ONE barrier per step (prefetch overlaps MFMA)
__global__ __launch_bounds__(256) void gemm_bnew(const unsigned char* __restrict__ Af8,
                                                 const unsigned char* __restrict__ Bf8,
                                                 const unsigned short* __restrict__ h1,
                                                 const unsigned short* __restrict__ h2,
                                                 const float* __restrict__ rowsum,
                                                 const float* __restrict__ colsum,
                                                 const float* __restrict__ gp,
                                                 const int* __restrict__ mask,
                                                 float* __restrict__ tmax,
                                                 float* __restrict__ tsum,
                                                 float* __restrict__ Bnew) {
    __shared__ __align__(16) unsigned char As[2][128 * 128];
    __shared__ __align__(16) unsigned char Bs[2][128 * 128];
    const int flat = blockIdx.x;
    const int x = flat & 7, s = flat >> 3;
    const int bb = x * 2 + (s >> 6);
    const int t = s & 63;
    const int i0 = (t >> 3) * 128, j0 = (t & 7) * 128;
    const unsigned char* A1 = Af8 + (size_t)bb * CC * CC + (size_t)i0 * CC;
    const unsigned char* B1 = Bf8 + (size_t)bb * CC * CC + (size_t)j0 * CC;
    const int w = threadIdx.x >> 6, lane = threadIdx.x & 63;
    const int wm = (w >> 1) * 64, wn = (w & 1) * 64;
    const int l16 = lane & 15, quad = lane >> 4;
    floatx4 acc[4][4] = {};
    const int sA = l16 & 7;
    const int c1 = (2 * quad) ^ sA;
    // fp8 main loop: 8 K-steps of 128, depth-1 prefetch, single barrier per step
    stage_async_b<1024>(As[0], A1, CC);
    stage_async_b<1024>(Bs[0], B1, CC);
    for (int kt = 0; kt < 8; kt++) {
        __syncthreads();  // drains tile-kt loads; orders prior reads vs upcoming overwrite
        if (kt < 7) {
            stage_async_b<1024>(As[(kt + 1) & 1], A1 + (kt + 1) * 128, CC);
            stage_async_b<1024>(Bs[(kt + 1) & 1], B1 + (kt + 1) * 128, CC);
        }
        const unsigned char* Ac = As[kt & 1];
        const unsigned char* Bc = Bs[kt & 1];
        intx8 a[4], bfr[4];
#pragma unroll
        for (int tm = 0; tm < 4; tm++) {
            const unsigned char* p = Ac + (size_t)(wm + tm * 16 + l16) * 128;
            int4 lo = *(const int4*)(p + c1 * 16);
            int4 hi = *(const int4*)(p + (c1 ^ 1) * 16);
            a[tm] = intx8{lo.x, lo.y, lo.z, lo.w, hi.x, hi.y, hi.z, hi.w};
        }
#pragma unroll
        for (int tn = 0; tn < 4; tn++) {
            const unsigned char* p = Bc + (size_t)(wn + tn * 16 + l16) * 128;
            int4 lo = *(const int4*)(p + c1 * 16);
            int4 hi = *(const int4*)(p + (c1 ^ 1) * 16);
            bfr[tn] = intx8{lo.x, lo.y, lo.z, lo.w, hi.x, hi.y, hi.z, hi.w};
        }
#pragma unroll
        for (int tm = 0; tm < 4; tm++)
#pragma unroll
            for (int tn = 0; tn < 4; tn++)
                acc[tm][tn] = __builtin_amdgcn_mfma_scale_f32_16x16x128_f8f6f4(
                    a[tm], bfr[tn], acc[tm][tn], 0, 0, 0, 127, 0, 127);
    }
    // prefetch bf16 tile 0 (safe: As[0]/Bs[0] reads were consumed before kt=7's barrier),
    // then do the scale epilogue VALU under the load latency
    const unsigned short* A2 = h1 + (size_t)bb * CC * DD + (size_t)i0 * DD;
    const unsigned short* B2 = h2 + (size_t)bb * CC * DD + (size_t)j0 * DD;
    stage_async_b<1024>(As[0], A2, DD * 2);
    stage_async_b<1024>(Bs[0], B2, DD * 2);
    const float gm = gp[0];
    float cinv[4], rsc[4][4];
#pragma unroll
    for (int tn = 0; tn < 4; tn++) cinv[tn] = 1.f / colsum[bb * CC + j0 + wn + tn * 16 + l16];
#pragma unroll
    for (int tm = 0; tm < 4; tm++)
#pragma unroll
        for (int i = 0; i < 4; i++)
            rsc[tm][i] = gm / rowsum[bb * CC + i0 + wm + tm * 16 + quad * 4 + i];
#pragma unroll
    for (int tm = 0; tm < 4; tm++)
#pragma unroll
        for (int tn = 0; tn < 4; tn++)
#pragma unroll
            for (int i = 0; i < 4; i++) acc[tm][tn][i] *= rsc[tm][i] * cinv[tn];
    for (int kt = 0; kt < 2; kt++) {
        __syncthreads();
        if (kt == 0) {
            stage_async_b<1024>(As[1], A2 + 64, DD * 2);
            stage_async_b<1024>(Bs[1], B2 + 64, DD * 2);
        }
        mfma_tile<4, 4>((const unsigned short(*)[64])As[kt], (const unsigned short(*)[64])Bs[kt], wm, wn, acc);
    }
    // epilogue: diag-zero, write Bnew, emit split-softmax stats per 64-col half
    int mcol[4];
#pragma unroll
    for (int tn = 0; tn < 4; tn++) mcol[tn] = mask[bb * CC + j0 + wn + tn * 16 + l16];
    float* out = Bnew + (size_t)bb * CC * CC;
    const int sbase = (j0 >> 6) + (wn >> 6);  // 0..15 col-half index
#pragma unroll
    for (int tm = 0; tm < 4; tm++)
#pragma unroll
        for (int i = 0; i < 4; i++) {
            const int row = i0 + wm + tm * 16 + quad * 4 + i;
            float xq[4];
#pragma unroll
            for (int tn = 0; tn < 4; tn++) {
                const int col = j0 + wn + tn * 16 + l16;
                float v = acc[tm][tn][i];
                if (row == col) v = 0.f;
                out[(size_t)row * CC + col] = v;
                xq[tn] = mcol[tn] ? v : NEGV;
            }
            float m = fmaxf(fmaxf(xq[0], xq[1]), fmaxf(xq[2], xq[3]));
#pragma unroll
            for (int off = 1; off < 16; off <<= 1) m = fmaxf(m, __shfl_xor(m, off, 64));
            float ss = __expf(xq[0] - m) + __expf(xq[1] - m) + __expf(xq[2] - m) + __expf(xq[3] - m);
#pragma unroll
            for (int off = 1; off < 16; off <<= 1) ss += __shfl_xor(ss, off, 64);
            if (l16 == 0) {
                const size_t sidx = ((size_t)bb * CC + row) * 16 + sbase;
                tmax[sidx] = m;
                tsum[sidx] = ss;
            }
        }
}

// ---------------- fused: row-softmax(Bnew) staged on the fly + h_tmp GEMM +
//                  m'=[ht,h.ht,h] in LDS + dual gate GEMM + blend
__global__ __launch_bounds__(256) void gemm_fuse(const float* __restrict__ Bn,
                                                 const float* __restrict__ tmax,
                                                 const float* __restrict__ tsum,
                                                 const int* __restrict__ mask,
                                                 const unsigned short* __restrict__ h_bT,
                                                 const float* __restrict__ h,
                                                 const unsigned short* __restrict__ wc,
                                                 float* __restrict__ o) {
    __shared__ unsigned short mPb[64 * MP];
    __shared__ unsigned short S1[2][64][64];
    __shared__ unsigned short S2[2][128][64];
    __shared__ unsigned short Wb[2][128][64];
    __shared__ float rowM[64], rowInv[64];
    const int flat = blockIdx.x;
    const int b = (flat & 7) * 2 + (flat >> 7);       // XCD-pinned: 2 batches per XCD
    const int i0 = ((flat >> 3) & 15) * 64;
    const int tid = threadIdx.x;
    const int w = tid >> 6, lane = tid & 63;
    const int wm = (w >> 1) * 32, wn = (w & 1) * 64;
    const int quad = lane >> 4, l16 = lane & 15;

    // combine per-half stats -> per-row (max, 1/sum)
    if (tid < 64) {
        const float* pm = tmax + ((size_t)b * CC + i0 + tid) * 16;
        const float* ps = tsum + ((size_t)b * CC + i0 + tid) * 16;
        float4 a0 = *(const float4*)(pm + 0), a1 = *(const float4*)(pm + 4);
        float4 a2 = *(const float4*)(pm + 8), a3 = *(const float4*)(pm + 12);
        float4 s0 = *(const float4*)(ps + 0), s1 = *(const float4*)(ps + 4);
        float4 s2 = *(const float4*)(ps + 8), s3 = *(const float4*)(ps + 12);
        float mx = fmaxf(fmaxf(fmaxf(a0.x, a0.y), fmaxf(a0.z, a0.w)),
                         fmaxf(fmaxf(a1.x, a1.y), fmaxf(a1.z, a1.w)));
        mx = fmaxf(mx, fmaxf(fmaxf(fmaxf(a2.x, a2.y), fmaxf(a2.z, a2.w)),
                             fmaxf(fmaxf(a3.x, a3.y), fmaxf(a3.z, a3.w))));
        float s = __expf(a0.x - mx) * s0.x + __expf(a0.y - mx) * s0.y +
                  __expf(a0.z - mx) * s0.z + __expf(a0.w - mx) * s0.w +
                  __expf(a1.x - mx) * s1.x + __expf(a1.y - mx) * s1.y +
                  __expf(a1.z - mx) * s1.z + __expf(a1.w - mx) * s1.w +
                  __expf(a2.x - mx) * s2.x + __expf(a2.y - mx) * s2.y +
                  __expf(a2.z - mx) * s2.z + __expf(a2.w - mx) * s2.w +
                  __expf(a3.x - mx) * s3.x + __expf(a3.y - mx) * s3.y +
                  __expf(a3.z - mx) * s3.z + __expf(a3.w - mx) * s3.w;
        rowM[tid] = mx;
        rowInv[tid] = 1.f / s;
    }

    const float* A = Bn + ((size_t)b * CC + i0) * CC;
    const unsigned short* Bt = h_bT + (size_t)b * DD * CC;
    const int sr = tid >> 4, sc4 = (tid & 15) * 4;
    const int swz = (((sc4 >> 3) ^ (sr & 7)) << 4) + ((sc4 >> 2) & 1) * 8;  // byte off in 128B row

    float4 vc[4], vn[4];
    int4 mc, mn;
#pragma unroll
    for (int u = 0; u < 4; u++) vc[u] = *(const float4*)(A + (size_t)(sr + u * 16) * CC + sc4);
    mc = *(const int4*)(mask + b * CC + sc4);
    stage_async_b<1024>(S2[0], Bt, CC * 2);
#pragma unroll
    for (int u = 0; u < 4; u++) vn[u] = *(const float4*)(A + (size_t)(sr + u * 16) * CC + 64 + sc4);
    mn = *(const int4*)(mask + b * CC + 64 + sc4);
    __syncthreads();  // rowM ready; vc arrived; S2[0] drained
#pragma unroll
    for (int u = 0; u < 4; u++) {
        const float m = rowM[sr + u * 16];
        ushort4 e;
        e.x = f2bf(__expf((mc.x ? vc[u].x : NEGV) - m));
        e.y = f2bf(__expf((mc.y ? vc[u].y : NEGV) - m));
        e.z = f2bf(__expf((mc.z ? vc[u].z : NEGV) - m));
        e.w = f2bf(__expf((mc.w ? vc[u].w : NEGV) - m));
        *(ushort4*)((unsigned char*)&S1[0][sr + u * 16][0] + swz) = e;
    }
    floatx4 acc[2][4] = {};
    for (int k = 0; k < 16; k++) {
        __syncthreads();  // S1[k&1] visible; S2[k&1] drained; vn regs arrived
        if (k < 15) {
#pragma unroll
            for (int u = 0; u < 4; u++) {
                const float m = rowM[sr + u * 16];
                ushort4 e;
                e.x = f2bf(__expf((mn.x ? vn[u].x : NEGV) - m));
                e.y = f2bf(__expf((mn.y ? vn[u].y : NEGV) - m));
                e.z = f2bf(__expf((mn.z ? vn[u].z : NEGV) - m));
                e.w = f2bf(__expf((mn.w ? vn[u].w : NEGV) - m));
                *(ushort4*)((unsigned char*)&S1[(k + 1) & 1][sr + u * 16][0] + swz) = e;
            }
            stage_async_b<1024>(S2[(k + 1) & 1], Bt + (k + 1) * 64, CC * 2);
        }
        if (k < 14) {
#pragma unroll
            for (int u = 0; u < 4; u++)
                vn[u] = *(const float4*)(A + (size_t)(sr + u * 16) * CC + (k + 2) * 64 + sc4);
            mn = *(const int4*)(mask + b * CC + (k + 2) * 64 + sc4);
        }
        if (k == 15) stage_async_b<1024>(Wb[0], wc, DD * 2);
        mfma_tile<2, 4>(S1[k & 1], S2[k & 1], wm, wn, acc);
    }
    floatx4 hv[2][4];
#pragma unroll
    for (int tm = 0; tm < 2; tm++)
#pragma unroll
        for (int i = 0; i < 4; i++) {
            const int row = wm + tm * 16 + quad * 4 + i;
            const float inv = rowInv[row];
#pragma unroll
            for (int tn = 0; tn < 4; tn++) {
                int d = wn + tn * 16 + l16;
                float hvv = h[((size_t)(i0 + row) * BB + b) * DD + d];
                hv[tm][tn][i] = hvv;
                float ht = acc[tm][tn][i] * inv;
                mPb[row * MP + d] = f2bf(ht);
                mPb[row * MP + 128 + d] = f2bf(hvv * ht);
                mPb[row * MP + 256 + d] = f2bf(hvv);
            }
        }
    floatx4 ar[2][4] = {}, ag[2][4] = {};
    for (int s = 0; s < 12; s++) {
        __syncthreads();
        if (s < 11) {
            const int s1 = s + 1;
            const int pan1 = s1 >> 1;              // (g*3+p) panel index 0..5
            const int k1 = (s1 & 1) * 64;          // half within panel
            stage_async_b<1024>(Wb[s1 & 1], wc + (size_t)pan1 * DD * DD + k1, DD * 2);
        }
        const int pan = s >> 1;
        const int koff = (pan % 3) * 128 + (s & 1) * 64;  // offset into m' K=384
        mfma_mixed(mPb + koff, Wb[s & 1], wm, wn, (s >= 6) ? ag : ar);
    }
#pragma unroll
    for (int tm = 0; tm < 2; tm++)
#pragma unroll
        for (int tn = 0; tn < 4; tn++)
#pragma unroll
            for (int i = 0; i < 4; i++) {
                int row = wm + tm * 16 + quad * 4 + i;
                int d = wn + tn * 16 + l16;
                float xv = fmaxf(ar[tm][tn][i], 0.f);
                float gv = 1.f / (1.f + __expf(-ag[tm][tn][i]));
                o[((size_t)(i0 + row) * BB + b) * DD + d] = xv * gv + (1.f - gv) * hv[tm][tn][i];
            }
}

extern "C" void kernel_launch(void* const* d_in, const int* in_sizes, int n_in,
                              void* d_out, int out_size, void* d_ws, size_t ws_size,
                              hipStream_t stream) {
    const float* h = (const float*)d_in[0];
    const int* h_mask = (const int*)d_in[1];
    const float* B_t = (const float*)d_in[2];
    const float* W1w = (const float*)d_in[3];
    const float* W1b = (const float*)d_in[4];
    const float* W2w = (const float*)d_in[5];
    const float* W2b = (const float*)d_in[6];
    const float* gp = (const float*)d_in[7];
    const float* Wrw = (const float*)d_in[8];
    const float* Wgw = (const float*)d_in[9];
    float* o = (float*)d_out;
    float* Bnew = o + (size_t)CC * BB * DD;

    char* ws = (char*)d_ws;
    size_t off = 0;
    auto alloc = [&](size_t bytes) { void* p = ws + off; off += bytes; return p; };
    unsigned short* h_bc = (unsigned short*)alloc((size_t)BB * CC * DD * 2);
    unsigned short* h_bT = (unsigned short*)alloc((size_t)BB * DD * CC * 2);
    unsigned short* h1 = (unsigned short*)alloc((size_t)BB * CC * DD * 2);
    unsigned short* h2 = (unsigned short*)alloc((size_t)BB * CC * DD * 2);
    unsigned short* w1t = (unsigned short*)alloc((size_t)DD * DD * 2);
    unsigned short* w2t = (unsigned short*)alloc((size_t)DD * DD * 2);
    unsigned short* wc = (unsigned short*)alloc((size_t)6 * DD * DD * 2);
    unsigned char* Em = (unsigned char*)alloc((size_t)BB * CC * CC);
    unsigned char* EmT = (unsigned char*)alloc((size_t)BB * CC * CC);
    float* stats = (float*)alloc((size_t)2 * BB * CC * 4);
    float* rowsum = stats;
    float* colsum = stats + (size_t)BB * CC;
    float* tmax = (float*)alloc((size_t)BB * CC * 16 * 4);
    float* tsum = (float*)alloc((size_t)BB * CC * 16 * 4);

    prep_all<<<dim3(608), 256, 0, stream>>>(h, h_bc, h_bT, W1w, W2w, Wrw, Wgw, w1t, w2t, wc, stats);
    expmask_dual<<<dim3(16, 16, 16), 256, 0, stream>>>(B_t, h_mask, Em, EmT, rowsum, colsum);
    gemm_h12<<<dim3(128, 1, 2), 256, 0, stream>>>(h_bc, w1t, w2t, W1b, W2b, h1, h2);
    gemm_bnew<<<dim3(1024), 256, 0, stream>>>(Em, EmT, h1, h2, rowsum, colsum, gp, h_mask, tmax, tsum, Bnew);
    gemm_fuse<<<dim3(256), 256, 0, stream>>>(Bnew, tmax, tsum, h_mask, h_bT, h, wc, o);
}

// Round 3
// 251.607 us; speedup vs baseline: 1.0176x; 1.0176x over previous
//
#include <hip/hip_runtime.h>
#include <hip/hip_bf16.h>
#include <math.h>

#define CC 1024
#define BB 16
#define DD 128
#define NEGV -1e30f
#define MP 392  // m' LDS row stride: 3*128 + 8 pad (16B-aligned rows)

typedef __attribute__((ext_vector_type(4))) float floatx4;
typedef __attribute__((ext_vector_type(8))) __bf16 bf16x8;
typedef __attribute__((ext_vector_type(8))) int intx8;

__device__ __forceinline__ unsigned short f2bf(float x) {
    unsigned int u = __float_as_uint(x);
    u = (u + 0x7FFFu + ((u >> 16) & 1u)) >> 16;
    return (unsigned short)u;
}
__device__ __forceinline__ float bf2f(unsigned short v) {
    return __uint_as_float((unsigned int)v << 16);
}

// ---------------- merged prep: h transpose/cast + weight cast/combine + stats zero
__global__ __launch_bounds__(256) void prep_all(const float* __restrict__ h,
                                                unsigned short* __restrict__ h_bc,
                                                unsigned short* __restrict__ h_bT,
                                                const float* __restrict__ w1, const float* __restrict__ w2,
                                                const float* __restrict__ wr, const float* __restrict__ wg,
                                                unsigned short* __restrict__ o1, unsigned short* __restrict__ o2,
                                                unsigned short* __restrict__ wc, float* __restrict__ stats) {
    __shared__ float tile[64][65];
    const int bid = blockIdx.x;
    if (bid < 512) {  // prep_h: (c0:16, d0:2, b:16)
        const int c0 = (bid & 15) * 64, d0 = ((bid >> 4) & 1) * 64, b = bid >> 5;
        const int tx = threadIdx.x & 63, ty = threadIdx.x >> 6;
#pragma unroll
        for (int i = 0; i < 16; i++) {
            int cl = ty + i * 4;
            float v = h[((size_t)(c0 + cl) * BB + b) * DD + d0 + tx];
            tile[cl][tx] = v;
            h_bc[((size_t)b * CC + c0 + cl) * DD + d0 + tx] = f2bf(v);
        }
        __syncthreads();
#pragma unroll
        for (int i = 0; i < 16; i++) {
            int dl = ty + i * 4;
            h_bT[((size_t)b * DD + d0 + dl) * CC + c0 + tx] = f2bf(tile[tx][dl]);
        }
    } else if (bid < 576) {  // prep_w
        int i = (bid - 512) * 256 + threadIdx.x;  // 0..16383
        int d = i >> 7, k = i & 127;
        o1[i] = f2bf(w1[i]);
        o2[i] = f2bf(w2[i]);
        const float* pr = wr + (size_t)d * 512;
        const float* pg = wg + (size_t)d * 512;
        wc[(size_t)(0 * 128 + d) * 128 + k] = f2bf(pr[128 + k] - pr[384 + k]);
        wc[(size_t)(1 * 128 + d) * 128 + k] = f2bf(pr[256 + k]);
        wc[(size_t)(2 * 128 + d) * 128 + k] = f2bf(pr[k] + pr[384 + k]);
        wc[(size_t)(3 * 128 + d) * 128 + k] = f2bf(pg[128 + k] - pg[384 + k]);
        wc[(size_t)(4 * 128 + d) * 128 + k] = f2bf(pg[256 + k]);
        wc[(size_t)(5 * 128 + d) * 128 + k] = f2bf(pg[k] + pg[384 + k]);
    } else {  // zero softmax-denominator accumulators (ws is poisoned)
        int i = ((bid - 576) * 256 + threadIdx.x) * 4;
        *(float4*)(stats + i) = float4{0.f, 0.f, 0.f, 0.f};
    }
}

// ---------------- fused exp+mask dual-layout emit (replaces both input softmaxes)
__global__ __launch_bounds__(256) void expmask_dual(const float* __restrict__ B_t,
                                                    const int* __restrict__ mask,
                                                    unsigned char* __restrict__ Em,
                                                    unsigned char* __restrict__ EmT,
                                                    float* __restrict__ rowsum,
                                                    float* __restrict__ colsum) {
    __shared__ float tile[64][65];
    __shared__ float cpart[16][65];
    const int b = blockIdx.z, i0 = blockIdx.x * 64, j0 = blockIdx.y * 64;
    const int tid = threadIdx.x;
    const int rr = tid >> 4, cc = tid & 15;
    const int4 mj4 = *(const int4*)(mask + b * CC + j0 + cc * 4);
    const int4 mi4 = *(const int4*)(mask + b * CC + i0 + cc * 4);
    const float fj[4] = {mj4.x ? 1.f : 0.f, mj4.y ? 1.f : 0.f, mj4.z ? 1.f : 0.f, mj4.w ? 1.f : 0.f};
    const float fi[4] = {mi4.x ? 1.f : 0.f, mi4.y ? 1.f : 0.f, mi4.z ? 1.f : 0.f, mi4.w ? 1.f : 0.f};
    float cp[4] = {0.f, 0.f, 0.f, 0.f};
#pragma unroll
    for (int p = 0; p < 4; p++) {
        const int r = p * 16 + rr;
        float4 v = *(const float4*)(B_t + ((size_t)b * CC + i0 + r) * CC + j0 + cc * 4);
        float e[4] = {__expf(fminf(v.x, 80.f)), __expf(fminf(v.y, 80.f)),
                      __expf(fminf(v.z, 80.f)), __expf(fminf(v.w, 80.f))};
        const float mi_r = mask[b * CC + i0 + r] ? 1.f : 0.f;
        float dsum = 0.f;
#pragma unroll
        for (int u = 0; u < 4; u++) {
            tile[r][cc * 4 + u] = e[u];
            cp[u] += e[u] * mi_r;
            dsum += e[u] * fj[u];
        }
        int pk = __builtin_amdgcn_cvt_pk_fp8_f32(e[0] * fj[0], e[1] * fj[1], 0, false);
        pk = __builtin_amdgcn_cvt_pk_fp8_f32(e[2] * fj[2], e[3] * fj[3], pk, true);
        *(int*)(Em + ((size_t)b * CC + i0 + r) * CC + j0 + cc * 4) = pk;
#pragma unroll
        for (int off = 1; off < 16; off <<= 1) dsum += __shfl_xor(dsum, off, 64);
        if (cc == 0) atomicAdd(&rowsum[b * CC + i0 + r], dsum);
    }
#pragma unroll
    for (int u = 0; u < 4; u++) cpart[rr][cc * 4 + u] = cp[u];
    __syncthreads();
    if (tid < 64) {
        float s = 0.f;
#pragma unroll
        for (int q = 0; q < 16; q++) s += cpart[q][tid];
        atomicAdd(&colsum[b * CC + j0 + tid], s);
    }
#pragma unroll
    for (int p = 0; p < 4; p++) {
        const int r2 = p * 16 + rr;
        float t0 = tile[cc * 4 + 0][r2] * fi[0];
        float t1 = tile[cc * 4 + 1][r2] * fi[1];
        float t2 = tile[cc * 4 + 2][r2] * fi[2];
        float t3 = tile[cc * 4 + 3][r2] * fi[3];
        int pk = __builtin_amdgcn_cvt_pk_fp8_f32(t0, t1, 0, false);
        pk = __builtin_amdgcn_cvt_pk_fp8_f32(t2, t3, pk, true);
        *(int*)(EmT + ((size_t)b * CC + j0 + r2) * CC + i0 + cc * 4) = pk;
    }
}

// ---------------- async staging: rows of 128 BYTES (8x16B chunks), XOR-swizzled
template <int NCH>
__device__ __forceinline__ void stage_async_b(void* dst, const void* src, int ld_bytes) {
    const int w = threadIdx.x >> 6, lane = threadIdx.x & 63;
#pragma unroll
    for (int base = w * 64; base < NCH; base += 256) {
        int ch = base + lane;
        int r = ch >> 3, c = ch & 7;
        int cg = c ^ (r & 7);
        __builtin_amdgcn_global_load_lds(
            (const __attribute__((address_space(1))) void*)((const unsigned char*)src + (size_t)r * ld_bytes + cg * 16),
            (__attribute__((address_space(3))) void*)((unsigned char*)dst + (size_t)base * 16),
            16, 0, 0);
    }
}

template <int TM, int TN>
__device__ __forceinline__ void mfma_tile(const unsigned short (*As)[64], const unsigned short (*Bs)[64],
                                          int arow0, int bcol0, floatx4 (&acc)[TM][TN]) {
    const int lane = threadIdx.x & 63;
    const int l16 = lane & 15, quad = lane >> 4;
    const int sw = l16 & 7;
#pragma unroll
    for (int kk = 0; kk < 2; ++kk) {
        bf16x8 a[TM], b[TN];
#pragma unroll
        for (int tm = 0; tm < TM; tm++)
            a[tm] = *(const bf16x8*)(&As[arow0 + tm * 16 + l16][((kk * 4 + quad) ^ sw) * 8]);
#pragma unroll
        for (int tn = 0; tn < TN; tn++)
            b[tn] = *(const bf16x8*)(&Bs[bcol0 + tn * 16 + l16][((kk * 4 + quad) ^ sw) * 8]);
#pragma unroll
        for (int tm = 0; tm < TM; tm++)
#pragma unroll
            for (int tn = 0; tn < TN; tn++)
                acc[tm][tn] = __builtin_amdgcn_mfma_f32_16x16x32_bf16(a[tm], b[tn], acc[tm][tn], 0, 0, 0);
    }
}

__device__ __forceinline__ void mfma_mixed(const unsigned short* mBase, const unsigned short (*Bs)[64],
                                           int arow0, int bcol0, floatx4 (&acc)[2][4]) {
    const int lane = threadIdx.x & 63;
    const int l16 = lane & 15, quad = lane >> 4;
    const int sw = l16 & 7;
#pragma unroll
    for (int kk = 0; kk < 2; ++kk) {
        bf16x8 a[2], bfr[4];
#pragma unroll
        for (int tm = 0; tm < 2; tm++)
            a[tm] = *(const bf16x8*)(mBase + (size_t)(arow0 + tm * 16 + l16) * MP + kk * 32 + quad * 8);
#pragma unroll
        for (int tn = 0; tn < 4; tn++)
            bfr[tn] = *(const bf16x8*)(&Bs[bcol0 + tn * 16 + l16][((kk * 4 + quad) ^ sw) * 8]);
#pragma unroll
        for (int tm = 0; tm < 2; tm++)
#pragma unroll
            for (int tn = 0; tn < 4; tn++)
                acc[tm][tn] = __builtin_amdgcn_mfma_f32_16x16x32_bf16(a[tm], bfr[tn], acc[tm][tn], 0, 0, 0);
    }
}

// ---------------- h1/h2: relu(h_bc @ W^T + bias), M=16384 N=128 K=128 (dbuf pipeline)
__global__ __launch_bounds__(256) void gemm_h12(const unsigned short* __restrict__ h_bc,
                                                const unsigned short* __restrict__ w1t,
                                                const unsigned short* __restrict__ w2t,
                                                const float* __restrict__ b1, const float* __restrict__ b2,
                                                unsigned short* __restrict__ h1, unsigned short* __restrict__ h2) {
    __shared__ unsigned short As[2][128][64];
    __shared__ unsigned short Bs[2][128][64];
    const unsigned short* W = blockIdx.z ? w2t : w1t;
    const float* bias = blockIdx.z ? b2 : b1;
    unsigned short* out = blockIdx.z ? h2 : h1;
    const int r0 = blockIdx.x * 128;
    const int w = threadIdx.x >> 6, lane = threadIdx.x & 63;
    const int wm = (w >> 1) * 64, wn = (w & 1) * 64;
    floatx4 acc[4][4] = {};
    stage_async_b<1024>(As[0], h_bc + (size_t)r0 * DD, DD * 2);
    stage_async_b<1024>(Bs[0], W, DD * 2);
    for (int kt = 0; kt < 2; kt++) {
        __syncthreads();
        if (kt == 0) {
            stage_async_b<1024>(As[1], h_bc + (size_t)r0 * DD + 64, DD * 2);
            stage_async_b<1024>(Bs[1], W + 64, DD * 2);
        }
        mfma_tile<4, 4>(As[kt], Bs[kt], wm, wn, acc);
    }
    const int quad = lane >> 4, l16 = lane & 15;
#pragma unroll
    for (int tm = 0; tm < 4; tm++)
#pragma unroll
        for (int tn = 0; tn < 4; tn++)
#pragma unroll
            for (int i = 0; i < 4; i++) {
                int row = r0 + wm + tm * 16 + quad * 4 + i;
                int col = wn + tn * 16 + l16;
                float v = acc[tm][tn][i] + bias[col];
                out[(size_t)row * DD + col] = f2bf(fmaxf(v, 0.f));
            }
}

// ---------------- B_new = h1@h2^T + gamma * rinv.cinv.(Em@EmT^T); also emits
//                  per-(row, 64-col-half) softmax stats (max, sum-of-exp) for gemm_fuse
//                  K-loop: dbuf LDS, raw s_barrier + COUNTED vmcnt (loads stay in flight
//                  across barriers; __syncthreads would force a vmcnt(0) drain)
__global__ __launch_bounds__(256) void gemm_bnew(const unsigned char* __restrict__ Af8,
                                                 const unsigned char* __restrict__ Bf8,
                                                 const unsigned short* __restrict__ h1,
                                                 const unsigned short* __restrict__ h2,
                                                 const float* __restrict__ rowsum,
                                                 const float* __restrict__ colsum,
                                                 const float* __restrict__ gp,
                                                 const int* __restrict__ mask,
                                                 float* __restrict__ tmax,
                                                 float* __restrict__ tsum,
                                                 float* __restrict__ Bnew) {
    __shared__ __align__(16) unsigned char As[2][128 * 128];
    __shared__ __align__(16) unsigned char Bs[2][128 * 128];
    const int flat = blockIdx.x;
    const int x = flat & 7, s = flat >> 3;
    const int bb = x * 2 + (s >> 6);
    const int t = s & 63;
    const int i0 = (t >> 3) * 128, j0 = (t & 7) * 128;
    const unsigned char* A1 = Af8 + (size_t)bb * CC * CC + (size_t)i0 * CC;
    const unsigned char* B1 = Bf8 + (size_t)bb * CC * CC + (size_t)j0 * CC;
    const int w = threadIdx.x >> 6, lane = threadIdx.x & 63;
    const int wm = (w >> 1) * 64, wn = (w & 1) * 64;
    const int l16 = lane & 15, quad = lane >> 4;
    floatx4 acc[4][4] = {};
    const int sA = l16 & 7;
    const int c1 = (2 * quad) ^ sA;
    // fp8 main loop: 8 K-steps of 128. Per-wave loads per tile = 8 (4 A + 4 B).
    // Steady state: stage(kt+1) -> vmcnt(8) [= tile kt landed, tile kt+1 in flight]
    // -> bar -> ds_read->regs -> lgkmcnt(0) -> bar [buf free] -> MFMA (covers loads).
    stage_async_b<1024>(As[0], A1, CC);
    stage_async_b<1024>(Bs[0], B1, CC);
    for (int kt = 0; kt < 8; kt++) {
        if (kt < 7) {
            stage_async_b<1024>(As[(kt + 1) & 1], A1 + (kt + 1) * 128, CC);
            stage_async_b<1024>(Bs[(kt + 1) & 1], B1 + (kt + 1) * 128, CC);
            asm volatile("s_waitcnt vmcnt(8)" ::: "memory");
        } else {
            asm volatile("s_waitcnt vmcnt(0)" ::: "memory");
        }
        __builtin_amdgcn_sched_barrier(0);
        asm volatile("s_barrier" ::: "memory");  // tile kt present in LDS (all waves)
        __builtin_amdgcn_sched_barrier(0);
        const unsigned char* Ac = As[kt & 1];
        const unsigned char* Bc = Bs[kt & 1];
        intx8 a[4], bfr[4];
#pragma unroll
        for (int tm = 0; tm < 4; tm++) {
            const unsigned char* p = Ac + (size_t)(wm + tm * 16 + l16) * 128;
            int4 lo = *(const int4*)(p + c1 * 16);
            int4 hi = *(const int4*)(p + (c1 ^ 1) * 16);
            a[tm] = intx8{lo.x, lo.y, lo.z, lo.w, hi.x, hi.y, hi.z, hi.w};
        }
#pragma unroll
        for (int tn = 0; tn < 4; tn++) {
            const unsigned char* p = Bc + (size_t)(wn + tn * 16 + l16) * 128;
            int4 lo = *(const int4*)(p + c1 * 16);
            int4 hi = *(const int4*)(p + (c1 ^ 1) * 16);
            bfr[tn] = intx8{lo.x, lo.y, lo.z, lo.w, hi.x, hi.y, hi.z, hi.w};
        }
        asm volatile("s_waitcnt lgkmcnt(0)" ::: "memory");
        __builtin_amdgcn_sched_barrier(0);
        asm volatile("s_barrier" ::: "memory");  // all waves done reading buf[kt&1]
        __builtin_amdgcn_sched_barrier(0);
#pragma unroll
        for (int tm = 0; tm < 4; tm++)
#pragma unroll
            for (int tn = 0; tn < 4; tn++)
                acc[tm][tn] = __builtin_amdgcn_mfma_scale_f32_16x16x128_f8f6f4(
                    a[tm], bfr[tn], acc[tm][tn], 0, 0, 0, 127, 0, 127);
    }
    // bf16 tail: prefetch tile 0 immediately (buf0 reads all in regs since kt=6's bar2),
    // run the scale epilogue under the load latency, then a 2-step pipelined tail.
    const unsigned short* A2 = h1 + (size_t)bb * CC * DD + (size_t)i0 * DD;
    const unsigned short* B2 = h2 + (size_t)bb * CC * DD + (size_t)j0 * DD;
    stage_async_b<1024>(As[0], A2, DD * 2);
    stage_async_b<1024>(Bs[0], B2, DD * 2);
    const float gm = gp[0];
    float cinv[4], rsc[4][4];
#pragma unroll
    for (int tn = 0; tn < 4; tn++) cinv[tn] = 1.f / colsum[bb * CC + j0 + wn + tn * 16 + l16];
#pragma unroll
    for (int tm = 0; tm < 4; tm++)
#pragma unroll
        for (int i = 0; i < 4; i++)
            rsc[tm][i] = gm / rowsum[bb * CC + i0 + wm + tm * 16 + quad * 4 + i];
#pragma unroll
    for (int tm = 0; tm < 4; tm++)
#pragma unroll
        for (int tn = 0; tn < 4; tn++)
#pragma unroll
            for (int i = 0; i < 4; i++) acc[tm][tn][i] *= rsc[tm][i] * cinv[tn];
    stage_async_b<1024>(As[1], A2 + 64, DD * 2);
    stage_async_b<1024>(Bs[1], B2 + 64, DD * 2);
    // vmcnt(8): tile-0 staging (oldest) complete; tile-1's 8 may remain in flight.
    asm volatile("s_waitcnt vmcnt(8)" ::: "memory");
    __builtin_amdgcn_sched_barrier(0);
    asm volatile("s_barrier" ::: "memory");
    __builtin_amdgcn_sched_barrier(0);
    mfma_tile<4, 4>((const unsigned short(*)[64])As[0], (const unsigned short(*)[64])Bs[0], wm, wn, acc);
    asm volatile("s_waitcnt vmcnt(0)" ::: "memory");
    __builtin_amdgcn_sched_barrier(0);
    asm volatile("s_barrier" ::: "memory");
    __builtin_amdgcn_sched_barrier(0);
    mfma_tile<4, 4>((const unsigned short(*)[64])As[1], (const unsigned short(*)[64])Bs[1], wm, wn, acc);
    // epilogue: diag-zero, write Bnew, emit split-softmax stats per 64-col half
    int mcol[4];
#pragma unroll
    for (int tn = 0; tn < 4; tn++) mcol[tn] = mask[bb * CC + j0 + wn + tn * 16 + l16];
    float* out = Bnew + (size_t)bb * CC * CC;
    const int sbase = (j0 >> 6) + (wn >> 6);  // 0..15 col-half index
#pragma unroll
    for (int tm = 0; tm < 4; tm++)
#pragma unroll
        for (int i = 0; i < 4; i++) {
            const int row = i0 + wm + tm * 16 + quad * 4 + i;
            float xq[4];
#pragma unroll
            for (int tn = 0; tn < 4; tn++) {
                const int col = j0 + wn + tn * 16 + l16;
                float v = acc[tm][tn][i];
                if (row == col) v = 0.f;
                out[(size_t)row * CC + col] = v;
                xq[tn] = mcol[tn] ? v : NEGV;
            }
            float m = fmaxf(fmaxf(xq[0], xq[1]), fmaxf(xq[2], xq[3]));
#pragma unroll
            for (int off = 1; off < 16; off <<= 1) m = fmaxf(m, __shfl_xor(m, off, 64));
            float ss = __expf(xq[0] - m) + __expf(xq[1] - m) + __expf(xq[2] - m) + __expf(xq[3] - m);
#pragma unroll
            for (int off = 1; off < 16; off <<= 1) ss += __shfl_xor(ss, off, 64);
            if (l16 == 0) {
                const size_t sidx = ((size_t)bb * CC + row) * 16 + sbase;
                tmax[sidx] = m;
                tsum[sidx] = ss;
            }
        }
}

// ---------------- fused: row-softmax(Bnew) staged on the fly + h_tmp GEMM +
//                  m'=[ht,h.ht,h] in LDS + dual gate GEMM + blend
__global__ __launch_bounds__(256) void gemm_fuse(const float* __restrict__ Bn,
                                                 const float* __restrict__ tmax,
                                                 const float* __restrict__ tsum,
                                                 const int* __restrict__ mask,
                                                 const unsigned short* __restrict__ h_bT,
                                                 const float* __restrict__ h,
                                                 const unsigned short* __restrict__ wc,
                                                 float* __restrict__ o) {
    __shared__ unsigned short mPb[64 * MP];
    __shared__ unsigned short S1[2][64][64];
    __shared__ unsigned short S2[2][128][64];
    __shared__ unsigned short Wb[2][128][64];
    __shared__ float rowM[64], rowInv[64];
    const int flat = blockIdx.x;
    const int b = (flat & 7) * 2 + (flat >> 7);       // XCD-pinned: 2 batches per XCD
    const int i0 = ((flat >> 3) & 15) * 64;
    const int tid = threadIdx.x;
    const int w = tid >> 6, lane = tid & 63;
    const int wm = (w >> 1) * 32, wn = (w & 1) * 64;
    const int quad = lane >> 4, l16 = lane & 15;

    // combine per-half stats -> per-row (max, 1/sum)
    if (tid < 64) {
        const float* pm = tmax + ((size_t)b * CC + i0 + tid) * 16;
        const float* ps = tsum + ((size_t)b * CC + i0 + tid) * 16;
        float4 a0 = *(const float4*)(pm + 0), a1 = *(const float4*)(pm + 4);
        float4 a2 = *(const float4*)(pm + 8), a3 = *(const float4*)(pm + 12);
        float4 s0 = *(const float4*)(ps + 0), s1 = *(const float4*)(ps + 4);
        float4 s2 = *(const float4*)(ps + 8), s3 = *(const float4*)(ps + 12);
        float mx = fmaxf(fmaxf(fmaxf(a0.x, a0.y), fmaxf(a0.z, a0.w)),
                         fmaxf(fmaxf(a1.x, a1.y), fmaxf(a1.z, a1.w)));
        mx = fmaxf(mx, fmaxf(fmaxf(fmaxf(a2.x, a2.y), fmaxf(a2.z, a2.w)),
                             fmaxf(fmaxf(a3.x, a3.y), fmaxf(a3.z, a3.w))));
        float s = __expf(a0.x - mx) * s0.x + __expf(a0.y - mx) * s0.y +
                  __expf(a0.z - mx) * s0.z + __expf(a0.w - mx) * s0.w +
                  __expf(a1.x - mx) * s1.x + __expf(a1.y - mx) * s1.y +
                  __expf(a1.z - mx) * s1.z + __expf(a1.w - mx) * s1.w +
                  __expf(a2.x - mx) * s2.x + __expf(a2.y - mx) * s2.y +
                  __expf(a2.z - mx) * s2.z + __expf(a2.w - mx) * s2.w +
                  __expf(a3.x - mx) * s3.x + __expf(a3.y - mx) * s3.y +
                  __expf(a3.z - mx) * s3.z + __expf(a3.w - mx) * s3.w;
        rowM[tid] = mx;
        rowInv[tid] = 1.f / s;
    }

    const float* A = Bn + ((size_t)b * CC + i0) * CC;
    const unsigned short* Bt = h_bT + (size_t)b * DD * CC;
    const int sr = tid >> 4, sc4 = (tid & 15) * 4;
    const int swz = (((sc4 >> 3) ^ (sr & 7)) << 4) + ((sc4 >> 2) & 1) * 8;  // byte off in 128B row

    float4 vc[4], vn[4];
    int4 mc, mn;
#pragma unroll
    for (int u = 0; u < 4; u++) vc[u] = *(const float4*)(A + (size_t)(sr + u * 16) * CC + sc4);
    mc = *(const int4*)(mask + b * CC + sc4);
    stage_async_b<1024>(S2[0], Bt, CC * 2);
#pragma unroll
    for (int u = 0; u < 4; u++) vn[u] = *(const float4*)(A + (size_t)(sr + u * 16) * CC + 64 + sc4);
    mn = *(const int4*)(mask + b * CC + 64 + sc4);
    __syncthreads();  // rowM ready; vc arrived; S2[0] drained
#pragma unroll
    for (int u = 0; u < 4; u++) {
        const float m = rowM[sr + u * 16];
        ushort4 e;
        e.x = f2bf(__expf((mc.x ? vc[u].x : NEGV) - m));
        e.y = f2bf(__expf((mc.y ? vc[u].y : NEGV) - m));
        e.z = f2bf(__expf((mc.z ? vc[u].z : NEGV) - m));
        e.w = f2bf(__expf((mc.w ? vc[u].w : NEGV) - m));
        *(ushort4*)((unsigned char*)&S1[0][sr + u * 16][0] + swz) = e;
    }
    floatx4 acc[2][4] = {};
    for (int k = 0; k < 16; k++) {
        __syncthreads();  // S1[k&1] visible; S2[k&1] drained; vn regs arrived
        if (k < 15) {
#pragma unroll
            for (int u = 0; u < 4; u++) {
                const float m = rowM[sr + u * 16];
                ushort4 e;
                e.x = f2bf(__expf((mn.x ? vn[u].x : NEGV) - m));
                e.y = f2bf(__expf((mn.y ? vn[u].y : NEGV) - m));
                e.z = f2bf(__expf((mn.z ? vn[u].z : NEGV) - m));
                e.w = f2bf(__expf((mn.w ? vn[u].w : NEGV) - m));
                *(ushort4*)((unsigned char*)&S1[(k + 1) & 1][sr + u * 16][0] + swz) = e;
            }
            stage_async_b<1024>(S2[(k + 1) & 1], Bt + (k + 1) * 64, CC * 2);
        }
        if (k < 14) {
#pragma unroll
            for (int u = 0; u < 4; u++)
                vn[u] = *(const float4*)(A + (size_t)(sr + u * 16) * CC + (k + 2) * 64 + sc4);
            mn = *(const int4*)(mask + b * CC + (k + 2) * 64 + sc4);
        }
        if (k == 15) stage_async_b<1024>(Wb[0], wc, DD * 2);
        mfma_tile<2, 4>(S1[k & 1], S2[k & 1], wm, wn, acc);
    }
    floatx4 hv[2][4];
#pragma unroll
    for (int tm = 0; tm < 2; tm++)
#pragma unroll
        for (int i = 0; i < 4; i++) {
            const int row = wm + tm * 16 + quad * 4 + i;
            const float inv = rowInv[row];
#pragma unroll
            for (int tn = 0; tn < 4; tn++) {
                int d = wn + tn * 16 + l16;
                float hvv = h[((size_t)(i0 + row) * BB + b) * DD + d];
                hv[tm][tn][i] = hvv;
                float ht = acc[tm][tn][i] * inv;
                mPb[row * MP + d] = f2bf(ht);
                mPb[row * MP + 128 + d] = f2bf(hvv * ht);
                mPb[row * MP + 256 + d] = f2bf(hvv);
            }
        }
    floatx4 ar[2][4] = {}, ag[2][4] = {};
    for (int s = 0; s < 12; s++) {
        __syncthreads();
        if (s < 11) {
            const int s1 = s + 1;
            const int pan1 = s1 >> 1;              // (g*3+p) panel index 0..5
            const int k1 = (s1 & 1) * 64;          // half within panel
            stage_async_b<1024>(Wb[s1 & 1], wc + (size_t)pan1 * DD * DD + k1, DD * 2);
        }
        const int pan = s >> 1;
        const int koff = (pan % 3) * 128 + (s & 1) * 64;  // offset into m' K=384
        mfma_mixed(mPb + koff, Wb[s & 1], wm, wn, (s >= 6) ? ag : ar);
    }
#pragma unroll
    for (int tm = 0; tm < 2; tm++)
#pragma unroll
        for (int tn = 0; tn < 4; tn++)
#pragma unroll
            for (int i = 0; i < 4; i++) {
                int row = wm + tm * 16 + quad * 4 + i;
                int d = wn + tn * 16 + l16;
                float xv = fmaxf(ar[tm][tn][i], 0.f);
                float gv = 1.f / (1.f + __expf(-ag[tm][tn][i]));
                o[((size_t)(i0 + row) * BB + b) * DD + d] = xv * gv + (1.f - gv) * hv[tm][tn][i];
            }
}

extern "C" void kernel_launch(void* const* d_in, const int* in_sizes, int n_in,
                              void* d_out, int out_size, void* d_ws, size_t ws_size,
                              hipStream_t stream) {
    const float* h = (const float*)d_in[0];
    const int* h_mask = (const int*)d_in[1];
    const float* B_t = (const float*)d_in[2];
    const float* W1w = (const float*)d_in[3];
    const float* W1b = (const float*)d_in[4];
    const float* W2w = (const float*)d_in[5];
    const float* W2b = (const float*)d_in[6];
    const float* gp = (const float*)d_in[7];
    const float* Wrw = (const float*)d_in[8];
    const float* Wgw = (const float*)d_in[9];
    float* o = (float*)d_out;
    float* Bnew = o + (size_t)CC * BB * DD;

    char* ws = (char*)d_ws;
    size_t off = 0;
    auto alloc = [&](size_t bytes) { void* p = ws + off; off += bytes; return p; };
    unsigned short* h_bc = (unsigned short*)alloc((size_t)BB * CC * DD * 2);
    unsigned short* h_bT = (unsigned short*)alloc((size_t)BB * DD * CC * 2);
    unsigned short* h1 = (unsigned short*)alloc((size_t)BB * CC * DD * 2);
    unsigned short* h2 = (unsigned short*)alloc((size_t)BB * CC * DD * 2);
    unsigned short* w1t = (unsigned short*)alloc((size_t)DD * DD * 2);
    unsigned short* w2t = (unsigned short*)alloc((size_t)DD * DD * 2);
    unsigned short* wc = (unsigned short*)alloc((size_t)6 * DD * DD * 2);
    unsigned char* Em = (unsigned char*)alloc((size_t)BB * CC * CC);
    unsigned char* EmT = (unsigned char*)alloc((size_t)BB * CC * CC);
    float* stats = (float*)alloc((size_t)2 * BB * CC * 4);
    float* rowsum = stats;
    float* colsum = stats + (size_t)BB * CC;
    float* tmax = (float*)alloc((size_t)BB * CC * 16 * 4);
    float* tsum = (float*)alloc((size_t)BB * CC * 16 * 4);

    prep_all<<<dim3(608), 256, 0, stream>>>(h, h_bc, h_bT, W1w, W2w, Wrw, Wgw, w1t, w2t, wc, stats);
    expmask_dual<<<dim3(16, 16, 16), 256, 0, stream>>>(B_t, h_mask, Em, EmT, rowsum, colsum);
    gemm_h12<<<dim3(128, 1, 2), 256, 0, stream>>>(h_bc, w1t, w2t, W1b, W2b, h1, h2);
    gemm_bnew<<<dim3(1024), 256, 0, stream>>>(Em, EmT, h1, h2, rowsum, colsum, gp, h_mask, tmax, tsum, Bnew);
    gemm_fuse<<<dim3(256), 256, 0, stream>>>(Bnew, tmax, tsum, h_mask, h_bT, h, wc, o);
}

// Round 4
// 225.556 us; speedup vs baseline: 1.1352x; 1.1155x over previous
//
#include <hip/hip_runtime.h>
#include <hip/hip_bf16.h>
#include <math.h>

#define CC 1024
#define BB 16
#define DD 128
#define NEGV -1e30f
#define MP 392  // m' LDS row stride: 3*128 + 8 pad (16B-aligned rows)

typedef __attribute__((ext_vector_type(4))) float floatx4;
typedef __attribute__((ext_vector_type(8))) __bf16 bf16x8;
typedef __attribute__((ext_vector_type(8))) int intx8;

__device__ __forceinline__ unsigned short f2bf(float x) {
    unsigned int u = __float_as_uint(x);
    u = (u + 0x7FFFu + ((u >> 16) & 1u)) >> 16;
    return (unsigned short)u;
}
__device__ __forceinline__ float bf2f(unsigned short v) {
    return __uint_as_float((unsigned int)v << 16);
}

// ---------------- merged prep: h transpose/cast + weight cast/combine + stats zero
__global__ __launch_bounds__(256) void prep_all(const float* __restrict__ h,
                                                unsigned short* __restrict__ h_bc,
                                                unsigned short* __restrict__ h_bT,
                                                const float* __restrict__ w1, const float* __restrict__ w2,
                                                const float* __restrict__ wr, const float* __restrict__ wg,
                                                unsigned short* __restrict__ o1, unsigned short* __restrict__ o2,
                                                unsigned short* __restrict__ wc, float* __restrict__ stats) {
    __shared__ float tile[64][65];
    const int bid = blockIdx.x;
    if (bid < 512) {  // prep_h: (c0:16, d0:2, b:16)
        const int c0 = (bid & 15) * 64, d0 = ((bid >> 4) & 1) * 64, b = bid >> 5;
        const int tx = threadIdx.x & 63, ty = threadIdx.x >> 6;
#pragma unroll
        for (int i = 0; i < 16; i++) {
            int cl = ty + i * 4;
            float v = h[((size_t)(c0 + cl) * BB + b) * DD + d0 + tx];
            tile[cl][tx] = v;
            h_bc[((size_t)b * CC + c0 + cl) * DD + d0 + tx] = f2bf(v);
        }
        __syncthreads();
#pragma unroll
        for (int i = 0; i < 16; i++) {
            int dl = ty + i * 4;
            h_bT[((size_t)b * DD + d0 + dl) * CC + c0 + tx] = f2bf(tile[tx][dl]);
        }
    } else if (bid < 576) {  // prep_w
        int i = (bid - 512) * 256 + threadIdx.x;  // 0..16383
        int d = i >> 7, k = i & 127;
        o1[i] = f2bf(w1[i]);
        o2[i] = f2bf(w2[i]);
        const float* pr = wr + (size_t)d * 512;
        const float* pg = wg + (size_t)d * 512;
        wc[(size_t)(0 * 128 + d) * 128 + k] = f2bf(pr[128 + k] - pr[384 + k]);
        wc[(size_t)(1 * 128 + d) * 128 + k] = f2bf(pr[256 + k]);
        wc[(size_t)(2 * 128 + d) * 128 + k] = f2bf(pr[k] + pr[384 + k]);
        wc[(size_t)(3 * 128 + d) * 128 + k] = f2bf(pg[128 + k] - pg[384 + k]);
        wc[(size_t)(4 * 128 + d) * 128 + k] = f2bf(pg[256 + k]);
        wc[(size_t)(5 * 128 + d) * 128 + k] = f2bf(pg[k] + pg[384 + k]);
    } else {  // zero softmax-denominator accumulators (ws is poisoned)
        int i = ((bid - 576) * 256 + threadIdx.x) * 4;
        *(float4*)(stats + i) = float4{0.f, 0.f, 0.f, 0.f};
    }
}

// ---------------- fused exp+mask dual-layout emit (replaces both input softmaxes)
__global__ __launch_bounds__(256) void expmask_dual(const float* __restrict__ B_t,
                                                    const int* __restrict__ mask,
                                                    unsigned char* __restrict__ Em,
                                                    unsigned char* __restrict__ EmT,
                                                    float* __restrict__ rowsum,
                                                    float* __restrict__ colsum) {
    __shared__ float tile[64][65];
    __shared__ float cpart[16][65];
    const int b = blockIdx.z, i0 = blockIdx.x * 64, j0 = blockIdx.y * 64;
    const int tid = threadIdx.x;
    const int rr = tid >> 4, cc = tid & 15;
    const int4 mj4 = *(const int4*)(mask + b * CC + j0 + cc * 4);
    const int4 mi4 = *(const int4*)(mask + b * CC + i0 + cc * 4);
    const float fj[4] = {mj4.x ? 1.f : 0.f, mj4.y ? 1.f : 0.f, mj4.z ? 1.f : 0.f, mj4.w ? 1.f : 0.f};
    const float fi[4] = {mi4.x ? 1.f : 0.f, mi4.y ? 1.f : 0.f, mi4.z ? 1.f : 0.f, mi4.w ? 1.f : 0.f};
    float cp[4] = {0.f, 0.f, 0.f, 0.f};
#pragma unroll
    for (int p = 0; p < 4; p++) {
        const int r = p * 16 + rr;
        float4 v = *(const float4*)(B_t + ((size_t)b * CC + i0 + r) * CC + j0 + cc * 4);
        float e[4] = {__expf(fminf(v.x, 80.f)), __expf(fminf(v.y, 80.f)),
                      __expf(fminf(v.z, 80.f)), __expf(fminf(v.w, 80.f))};
        const float mi_r = mask[b * CC + i0 + r] ? 1.f : 0.f;
        float dsum = 0.f;
#pragma unroll
        for (int u = 0; u < 4; u++) {
            tile[r][cc * 4 + u] = e[u];
            cp[u] += e[u] * mi_r;
            dsum += e[u] * fj[u];
        }
        int pk = __builtin_amdgcn_cvt_pk_fp8_f32(e[0] * fj[0], e[1] * fj[1], 0, false);
        pk = __builtin_amdgcn_cvt_pk_fp8_f32(e[2] * fj[2], e[3] * fj[3], pk, true);
        *(int*)(Em + ((size_t)b * CC + i0 + r) * CC + j0 + cc * 4) = pk;
#pragma unroll
        for (int off = 1; off < 16; off <<= 1) dsum += __shfl_xor(dsum, off, 64);
        if (cc == 0) atomicAdd(&rowsum[b * CC + i0 + r], dsum);
    }
#pragma unroll
    for (int u = 0; u < 4; u++) cpart[rr][cc * 4 + u] = cp[u];
    __syncthreads();
    if (tid < 64) {
        float s = 0.f;
#pragma unroll
        for (int q = 0; q < 16; q++) s += cpart[q][tid];
        atomicAdd(&colsum[b * CC + j0 + tid], s);
    }
#pragma unroll
    for (int p = 0; p < 4; p++) {
        const int r2 = p * 16 + rr;
        float t0 = tile[cc * 4 + 0][r2] * fi[0];
        float t1 = tile[cc * 4 + 1][r2] * fi[1];
        float t2 = tile[cc * 4 + 2][r2] * fi[2];
        float t3 = tile[cc * 4 + 3][r2] * fi[3];
        int pk = __builtin_amdgcn_cvt_pk_fp8_f32(t0, t1, 0, false);
        pk = __builtin_amdgcn_cvt_pk_fp8_f32(t2, t3, pk, true);
        *(int*)(EmT + ((size_t)b * CC + j0 + r2) * CC + i0 + cc * 4) = pk;
    }
}

// ---------------- async staging: rows of 128 BYTES (8x16B chunks), XOR-swizzled
template <int NCH>
__device__ __forceinline__ void stage_async_b(void* dst, const void* src, int ld_bytes) {
    const int w = threadIdx.x >> 6, lane = threadIdx.x & 63;
#pragma unroll
    for (int base = w * 64; base < NCH; base += 256) {
        int ch = base + lane;
        int r = ch >> 3, c = ch & 7;
        int cg = c ^ (r & 7);
        __builtin_amdgcn_global_load_lds(
            (const __attribute__((address_space(1))) void*)((const unsigned char*)src + (size_t)r * ld_bytes + cg * 16),
            (__attribute__((address_space(3))) void*)((unsigned char*)dst + (size_t)base * 16),
            16, 0, 0);
    }
}

template <int TM, int TN>
__device__ __forceinline__ void mfma_tile(const unsigned short (*As)[64], const unsigned short (*Bs)[64],
                                          int arow0, int bcol0, floatx4 (&acc)[TM][TN]) {
    const int lane = threadIdx.x & 63;
    const int l16 = lane & 15, quad = lane >> 4;
    const int sw = l16 & 7;
#pragma unroll
    for (int kk = 0; kk < 2; ++kk) {
        bf16x8 a[TM], b[TN];
#pragma unroll
        for (int tm = 0; tm < TM; tm++)
            a[tm] = *(const bf16x8*)(&As[arow0 + tm * 16 + l16][((kk * 4 + quad) ^ sw) * 8]);
#pragma unroll
        for (int tn = 0; tn < TN; tn++)
            b[tn] = *(const bf16x8*)(&Bs[bcol0 + tn * 16 + l16][((kk * 4 + quad) ^ sw) * 8]);
#pragma unroll
        for (int tm = 0; tm < TM; tm++)
#pragma unroll
            for (int tn = 0; tn < TN; tn++)
                acc[tm][tn] = __builtin_amdgcn_mfma_f32_16x16x32_bf16(a[tm], b[tn], acc[tm][tn], 0, 0, 0);
    }
}

__device__ __forceinline__ void mfma_mixed(const unsigned short* mBase, const unsigned short (*Bs)[64],
                                           int arow0, int bcol0, floatx4 (&acc)[2][4]) {
    const int lane = threadIdx.x & 63;
    const int l16 = lane & 15, quad = lane >> 4;
    const int sw = l16 & 7;
#pragma unroll
    for (int kk = 0; kk < 2; ++kk) {
        bf16x8 a[2], bfr[4];
#pragma unroll
        for (int tm = 0; tm < 2; tm++)
            a[tm] = *(const bf16x8*)(mBase + (size_t)(arow0 + tm * 16 + l16) * MP + kk * 32 + quad * 8);
#pragma unroll
        for (int tn = 0; tn < 4; tn++)
            bfr[tn] = *(const bf16x8*)(&Bs[bcol0 + tn * 16 + l16][((kk * 4 + quad) ^ sw) * 8]);
#pragma unroll
        for (int tm = 0; tm < 2; tm++)
#pragma unroll
            for (int tn = 0; tn < 4; tn++)
                acc[tm][tn] = __builtin_amdgcn_mfma_f32_16x16x32_bf16(a[tm], bfr[tn], acc[tm][tn], 0, 0, 0);
    }
}

// ---------------- h1/h2: relu(h_bc @ W^T + bias), M=16384 N=128 K=128 (dbuf pipeline)
__global__ __launch_bounds__(256) void gemm_h12(const unsigned short* __restrict__ h_bc,
                                                const unsigned short* __restrict__ w1t,
                                                const unsigned short* __restrict__ w2t,
                                                const float* __restrict__ b1, const float* __restrict__ b2,
                                                unsigned short* __restrict__ h1, unsigned short* __restrict__ h2) {
    __shared__ unsigned short As[2][128][64];
    __shared__ unsigned short Bs[2][128][64];
    const unsigned short* W = blockIdx.z ? w2t : w1t;
    const float* bias = blockIdx.z ? b2 : b1;
    unsigned short* out = blockIdx.z ? h2 : h1;
    const int r0 = blockIdx.x * 128;
    const int w = threadIdx.x >> 6, lane = threadIdx.x & 63;
    const int wm = (w >> 1) * 64, wn = (w & 1) * 64;
    floatx4 acc[4][4] = {};
    stage_async_b<1024>(As[0], h_bc + (size_t)r0 * DD, DD * 2);
    stage_async_b<1024>(Bs[0], W, DD * 2);
    for (int kt = 0; kt < 2; kt++) {
        __syncthreads();
        if (kt == 0) {
            stage_async_b<1024>(As[1], h_bc + (size_t)r0 * DD + 64, DD * 2);
            stage_async_b<1024>(Bs[1], W + 64, DD * 2);
        }
        mfma_tile<4, 4>(As[kt], Bs[kt], wm, wn, acc);
    }
    const int quad = lane >> 4, l16 = lane & 15;
#pragma unroll
    for (int tm = 0; tm < 4; tm++)
#pragma unroll
        for (int tn = 0; tn < 4; tn++)
#pragma unroll
            for (int i = 0; i < 4; i++) {
                int row = r0 + wm + tm * 16 + quad * 4 + i;
                int col = wn + tn * 16 + l16;
                float v = acc[tm][tn][i] + bias[col];
                out[(size_t)row * DD + col] = f2bf(fmaxf(v, 0.f));
            }
}

// ---------------- B_new = h1@h2^T + gamma * rinv.cinv.(Em@EmT^T); also emits
//                  per-(row, 64-col-half) softmax stats (max, sum-of-exp) for gemm_fuse
//                  Round-1 structure: single 32KB buffer, 2 barriers/K-step.
//                  (r2/r3 dbuf pipelines at 64KB LDS LOST: occupancy 4->2 blocks/CU
//                  outweighed intra-wave overlap — cross-block TLP is the winner here.)
__global__ __launch_bounds__(256) void gemm_bnew(const unsigned char* __restrict__ Af8,
                                                 const unsigned char* __restrict__ Bf8,
                                                 const unsigned short* __restrict__ h1,
                                                 const unsigned short* __restrict__ h2,
                                                 const float* __restrict__ rowsum,
                                                 const float* __restrict__ colsum,
                                                 const float* __restrict__ gp,
                                                 const int* __restrict__ mask,
                                                 float* __restrict__ tmax,
                                                 float* __restrict__ tsum,
                                                 float* __restrict__ Bnew) {
    __shared__ __align__(16) unsigned char As[128 * 128];
    __shared__ __align__(16) unsigned char Bs[128 * 128];
    const int flat = blockIdx.x;
    const int x = flat & 7, s = flat >> 3;
    const int bb = x * 2 + (s >> 6);
    const int t = s & 63;
    const int i0 = (t >> 3) * 128, j0 = (t & 7) * 128;
    const unsigned char* A1 = Af8 + (size_t)bb * CC * CC + (size_t)i0 * CC;
    const unsigned char* B1 = Bf8 + (size_t)bb * CC * CC + (size_t)j0 * CC;
    const int w = threadIdx.x >> 6, lane = threadIdx.x & 63;
    const int wm = (w >> 1) * 64, wn = (w & 1) * 64;
    const int l16 = lane & 15, quad = lane >> 4;
    floatx4 acc[4][4] = {};
    const int sA = l16 & 7;
    const int c1 = (2 * quad) ^ sA;
    for (int k0 = 0; k0 < CC; k0 += 128) {
        stage_async_b<1024>(As, A1 + k0, CC);
        stage_async_b<1024>(Bs, B1 + k0, CC);
        __syncthreads();
        intx8 a[4], bfr[4];
#pragma unroll
        for (int tm = 0; tm < 4; tm++) {
            const unsigned char* p = As + (size_t)(wm + tm * 16 + l16) * 128;
            int4 lo = *(const int4*)(p + c1 * 16);
            int4 hi = *(const int4*)(p + (c1 ^ 1) * 16);
            a[tm] = intx8{lo.x, lo.y, lo.z, lo.w, hi.x, hi.y, hi.z, hi.w};
        }
#pragma unroll
        for (int tn = 0; tn < 4; tn++) {
            const unsigned char* p = Bs + (size_t)(wn + tn * 16 + l16) * 128;
            int4 lo = *(const int4*)(p + c1 * 16);
            int4 hi = *(const int4*)(p + (c1 ^ 1) * 16);
            bfr[tn] = intx8{lo.x, lo.y, lo.z, lo.w, hi.x, hi.y, hi.z, hi.w};
        }
#pragma unroll
        for (int tm = 0; tm < 4; tm++)
#pragma unroll
            for (int tn = 0; tn < 4; tn++)
                acc[tm][tn] = __builtin_amdgcn_mfma_scale_f32_16x16x128_f8f6f4(
                    a[tm], bfr[tn], acc[tm][tn], 0, 0, 0, 127, 0, 127);
        __syncthreads();
    }
    // prefetch bf16 tile 0 (safe: As/Bs reads were consumed before the trailing barrier),
    // then do the scale epilogue VALU under the load latency
    const unsigned short* A2 = h1 + (size_t)bb * CC * DD + (size_t)i0 * DD;
    const unsigned short* B2 = h2 + (size_t)bb * CC * DD + (size_t)j0 * DD;
    stage_async_b<1024>(As, A2, DD * 2);
    stage_async_b<1024>(Bs, B2, DD * 2);
    const float gm = gp[0];
    float cinv[4], rsc[4][4];
#pragma unroll
    for (int tn = 0; tn < 4; tn++) cinv[tn] = 1.f / colsum[bb * CC + j0 + wn + tn * 16 + l16];
#pragma unroll
    for (int tm = 0; tm < 4; tm++)
#pragma unroll
        for (int i = 0; i < 4; i++)
            rsc[tm][i] = gm / rowsum[bb * CC + i0 + wm + tm * 16 + quad * 4 + i];
#pragma unroll
    for (int tm = 0; tm < 4; tm++)
#pragma unroll
        for (int tn = 0; tn < 4; tn++)
#pragma unroll
            for (int i = 0; i < 4; i++) acc[tm][tn][i] *= rsc[tm][i] * cinv[tn];
    for (int kt = 0; kt < 2; kt++) {
        __syncthreads();
        mfma_tile<4, 4>((const unsigned short(*)[64])As, (const unsigned short(*)[64])Bs, wm, wn, acc);
        __syncthreads();
        if (kt == 0) {
            stage_async_b<1024>(As, A2 + 64, DD * 2);
            stage_async_b<1024>(Bs, B2 + 64, DD * 2);
        }
    }
    // epilogue: diag-zero, write Bnew, emit split-softmax stats per 64-col half
    int mcol[4];
#pragma unroll
    for (int tn = 0; tn < 4; tn++) mcol[tn] = mask[bb * CC + j0 + wn + tn * 16 + l16];
    float* out = Bnew + (size_t)bb * CC * CC;
    const int sbase = (j0 >> 6) + (wn >> 6);  // 0..15 col-half index
#pragma unroll
    for (int tm = 0; tm < 4; tm++)
#pragma unroll
        for (int i = 0; i < 4; i++) {
            const int row = i0 + wm + tm * 16 + quad * 4 + i;
            float xq[4];
#pragma unroll
            for (int tn = 0; tn < 4; tn++) {
                const int col = j0 + wn + tn * 16 + l16;
                float v = acc[tm][tn][i];
                if (row == col) v = 0.f;
                out[(size_t)row * CC + col] = v;
                xq[tn] = mcol[tn] ? v : NEGV;
            }
            float m = fmaxf(fmaxf(xq[0], xq[1]), fmaxf(xq[2], xq[3]));
#pragma unroll
            for (int off = 1; off < 16; off <<= 1) m = fmaxf(m, __shfl_xor(m, off, 64));
            float ss = __expf(xq[0] - m) + __expf(xq[1] - m) + __expf(xq[2] - m) + __expf(xq[3] - m);
#pragma unroll
            for (int off = 1; off < 16; off <<= 1) ss += __shfl_xor(ss, off, 64);
            if (l16 == 0) {
                const size_t sidx = ((size_t)bb * CC + row) * 16 + sbase;
                tmax[sidx] = m;
                tsum[sidx] = ss;
            }
        }
}

// ---------------- fused: row-softmax(Bnew) staged on the fly + h_tmp GEMM +
//                  m'=[ht,h.ht,h] in LDS + dual gate GEMM + blend
__global__ __launch_bounds__(256) void gemm_fuse(const float* __restrict__ Bn,
                                                 const float* __restrict__ tmax,
                                                 const float* __restrict__ tsum,
                                                 const int* __restrict__ mask,
                                                 const unsigned short* __restrict__ h_bT,
                                                 const float* __restrict__ h,
                                                 const unsigned short* __restrict__ wc,
                                                 float* __restrict__ o) {
    __shared__ unsigned short mPb[64 * MP];
    __shared__ unsigned short S1[2][64][64];
    __shared__ unsigned short S2[2][128][64];
    __shared__ unsigned short Wb[2][128][64];
    __shared__ float rowM[64], rowInv[64];
    const int flat = blockIdx.x;
    const int b = (flat & 7) * 2 + (flat >> 7);       // XCD-pinned: 2 batches per XCD
    const int i0 = ((flat >> 3) & 15) * 64;
    const int tid = threadIdx.x;
    const int w = tid >> 6, lane = tid & 63;
    const int wm = (w >> 1) * 32, wn = (w & 1) * 64;
    const int quad = lane >> 4, l16 = lane & 15;

    // combine per-half stats -> per-row (max, 1/sum)
    if (tid < 64) {
        const float* pm = tmax + ((size_t)b * CC + i0 + tid) * 16;
        const float* ps = tsum + ((size_t)b * CC + i0 + tid) * 16;
        float4 a0 = *(const float4*)(pm + 0), a1 = *(const float4*)(pm + 4);
        float4 a2 = *(const float4*)(pm + 8), a3 = *(const float4*)(pm + 12);
        float4 s0 = *(const float4*)(ps + 0), s1 = *(const float4*)(ps + 4);
        float4 s2 = *(const float4*)(ps + 8), s3 = *(const float4*)(ps + 12);
        float mx = fmaxf(fmaxf(fmaxf(a0.x, a0.y), fmaxf(a0.z, a0.w)),
                         fmaxf(fmaxf(a1.x, a1.y), fmaxf(a1.z, a1.w)));
        mx = fmaxf(mx, fmaxf(fmaxf(fmaxf(a2.x, a2.y), fmaxf(a2.z, a2.w)),
                             fmaxf(fmaxf(a3.x, a3.y), fmaxf(a3.z, a3.w))));
        float s = __expf(a0.x - mx) * s0.x + __expf(a0.y - mx) * s0.y +
                  __expf(a0.z - mx) * s0.z + __expf(a0.w - mx) * s0.w +
                  __expf(a1.x - mx) * s1.x + __expf(a1.y - mx) * s1.y +
                  __expf(a1.z - mx) * s1.z + __expf(a1.w - mx) * s1.w +
                  __expf(a2.x - mx) * s2.x + __expf(a2.y - mx) * s2.y +
                  __expf(a2.z - mx) * s2.z + __expf(a2.w - mx) * s2.w +
                  __expf(a3.x - mx) * s3.x + __expf(a3.y - mx) * s3.y +
                  __expf(a3.z - mx) * s3.z + __expf(a3.w - mx) * s3.w;
        rowM[tid] = mx;
        rowInv[tid] = 1.f / s;
    }

    const float* A = Bn + ((size_t)b * CC + i0) * CC;
    const unsigned short* Bt = h_bT + (size_t)b * DD * CC;
    const int sr = tid >> 4, sc4 = (tid & 15) * 4;
    const int swz = (((sc4 >> 3) ^ (sr & 7)) << 4) + ((sc4 >> 2) & 1) * 8;  // byte off in 128B row

    float4 vc[4], vn[4];
    int4 mc, mn;
#pragma unroll
    for (int u = 0; u < 4; u++) vc[u] = *(const float4*)(A + (size_t)(sr + u * 16) * CC + sc4);
    mc = *(const int4*)(mask + b * CC + sc4);
    stage_async_b<1024>(S2[0], Bt, CC * 2);
#pragma unroll
    for (int u = 0; u < 4; u++) vn[u] = *(const float4*)(A + (size_t)(sr + u * 16) * CC + 64 + sc4);
    mn = *(const int4*)(mask + b * CC + 64 + sc4);
    __syncthreads();  // rowM ready; vc arrived; S2[0] drained
#pragma unroll
    for (int u = 0; u < 4; u++) {
        const float m = rowM[sr + u * 16];
        ushort4 e;
        e.x = f2bf(__expf((mc.x ? vc[u].x : NEGV) - m));
        e.y = f2bf(__expf((mc.y ? vc[u].y : NEGV) - m));
        e.z = f2bf(__expf((mc.z ? vc[u].z : NEGV) - m));
        e.w = f2bf(__expf((mc.w ? vc[u].w : NEGV) - m));
        *(ushort4*)((unsigned char*)&S1[0][sr + u * 16][0] + swz) = e;
    }
    floatx4 acc[2][4] = {};
    for (int k = 0; k < 16; k++) {
        __syncthreads();  // S1[k&1] visible; S2[k&1] drained; vn regs arrived
        if (k < 15) {
#pragma unroll
            for (int u = 0; u < 4; u++) {
                const float m = rowM[sr + u * 16];
                ushort4 e;
                e.x = f2bf(__expf((mn.x ? vn[u].x : NEGV) - m));
                e.y = f2bf(__expf((mn.y ? vn[u].y : NEGV) - m));
                e.z = f2bf(__expf((mn.z ? vn[u].z : NEGV) - m));
                e.w = f2bf(__expf((mn.w ? vn[u].w : NEGV) - m));
                *(ushort4*)((unsigned char*)&S1[(k + 1) & 1][sr + u * 16][0] + swz) = e;
            }
            stage_async_b<1024>(S2[(k + 1) & 1], Bt + (k + 1) * 64, CC * 2);
        }
        if (k < 14) {
#pragma unroll
            for (int u = 0; u < 4; u++)
                vn[u] = *(const float4*)(A + (size_t)(sr + u * 16) * CC + (k + 2) * 64 + sc4);
            mn = *(const int4*)(mask + b * CC + (k + 2) * 64 + sc4);
        }
        if (k == 15) stage_async_b<1024>(Wb[0], wc, DD * 2);
        mfma_tile<2, 4>(S1[k & 1], S2[k & 1], wm, wn, acc);
    }
    floatx4 hv[2][4];
#pragma unroll
    for (int tm = 0; tm < 2; tm++)
#pragma unroll
        for (int i = 0; i < 4; i++) {
            const int row = wm + tm * 16 + quad * 4 + i;
            const float inv = rowInv[row];
#pragma unroll
            for (int tn = 0; tn < 4; tn++) {
                int d = wn + tn * 16 + l16;
                float hvv = h[((size_t)(i0 + row) * BB + b) * DD + d];
                hv[tm][tn][i] = hvv;
                float ht = acc[tm][tn][i] * inv;
                mPb[row * MP + d] = f2bf(ht);
                mPb[row * MP + 128 + d] = f2bf(hvv * ht);
                mPb[row * MP + 256 + d] = f2bf(hvv);
            }
        }
    floatx4 ar[2][4] = {}, ag[2][4] = {};
    for (int s = 0; s < 12; s++) {
        __syncthreads();
        if (s < 11) {
            const int s1 = s + 1;
            const int pan1 = s1 >> 1;              // (g*3+p) panel index 0..5
            const int k1 = (s1 & 1) * 64;          // half within panel
            stage_async_b<1024>(Wb[s1 & 1], wc + (size_t)pan1 * DD * DD + k1, DD * 2);
        }
        const int pan = s >> 1;
        const int koff = (pan % 3) * 128 + (s & 1) * 64;  // offset into m' K=384
        mfma_mixed(mPb + koff, Wb[s & 1], wm, wn, (s >= 6) ? ag : ar);
    }
#pragma unroll
    for (int tm = 0; tm < 2; tm++)
#pragma unroll
        for (int tn = 0; tn < 4; tn++)
#pragma unroll
            for (int i = 0; i < 4; i++) {
                int row = wm + tm * 16 + quad * 4 + i;
                int d = wn + tn * 16 + l16;
                float xv = fmaxf(ar[tm][tn][i], 0.f);
                float gv = 1.f / (1.f + __expf(-ag[tm][tn][i]));
                o[((size_t)(i0 + row) * BB + b) * DD + d] = xv * gv + (1.f - gv) * hv[tm][tn][i];
            }
}

extern "C" void kernel_launch(void* const* d_in, const int* in_sizes, int n_in,
                              void* d_out, int out_size, void* d_ws, size_t ws_size,
                              hipStream_t stream) {
    const float* h = (const float*)d_in[0];
    const int* h_mask = (const int*)d_in[1];
    const float* B_t = (const float*)d_in[2];
    const float* W1w = (const float*)d_in[3];
    const float* W1b = (const float*)d_in[4];
    const float* W2w = (const float*)d_in[5];
    const float* W2b = (const float*)d_in[6];
    const float* gp = (const float*)d_in[7];
    const float* Wrw = (const float*)d_in[8];
    const float* Wgw = (const float*)d_in[9];
    float* o = (float*)d_out;
    float* Bnew = o + (size_t)CC * BB * DD;

    char* ws = (char*)d_ws;
    size_t off = 0;
    auto alloc = [&](size_t bytes) { void* p = ws + off; off += bytes; return p; };
    unsigned short* h_bc = (unsigned short*)alloc((size_t)BB * CC * DD * 2);
    unsigned short* h_bT = (unsigned short*)alloc((size_t)BB * DD * CC * 2);
    unsigned short* h1 = (unsigned short*)alloc((size_t)BB * CC * DD * 2);
    unsigned short* h2 = (unsigned short*)alloc((size_t)BB * CC * DD * 2);
    unsigned short* w1t = (unsigned short*)alloc((size_t)DD * DD * 2);
    unsigned short* w2t = (unsigned short*)alloc((size_t)DD * DD * 2);
    unsigned short* wc = (unsigned short*)alloc((size_t)6 * DD * DD * 2);
    unsigned char* Em = (unsigned char*)alloc((size_t)BB * CC * CC);
    unsigned char* EmT = (unsigned char*)alloc((size_t)BB * CC * CC);
    float* stats = (float*)alloc((size_t)2 * BB * CC * 4);
    float* rowsum = stats;
    float* colsum = stats + (size_t)BB * CC;
    float* tmax = (float*)alloc((size_t)BB * CC * 16 * 4);
    float* tsum = (float*)alloc((size_t)BB * CC * 16 * 4);

    prep_all<<<dim3(608), 256, 0, stream>>>(h, h_bc, h_bT, W1w, W2w, Wrw, Wgw, w1t, w2t, wc, stats);
    expmask_dual<<<dim3(16, 16, 16), 256, 0, stream>>>(B_t, h_mask, Em, EmT, rowsum, colsum);
    gemm_h12<<<dim3(128, 1, 2), 256, 0, stream>>>(h_bc, w1t, w2t, W1b, W2b, h1, h2);
    gemm_bnew<<<dim3(1024), 256, 0, stream>>>(Em, EmT, h1, h2, rowsum, colsum, gp, h_mask, tmax, tsum, Bnew);
    gemm_fuse<<<dim3(256), 256, 0, stream>>>(Bnew, tmax, tsum, h_mask, h_bT, h, wc, o);
}